// Round 1
// baseline (811.021 us; speedup 1.0000x reference)
//
#include <hip/hip_runtime.h>
#include <math.h>

#define N_NODES 8192
#define NFEAT 512
#define NHID 64
#define NHEADS 8
#define NCLASS 40
#define NCHUNK 128
#define CHUNK 64

// ---------------- GEMM1: Wh[i, h*64+f] = sum_c x[i,c] * W_heads[h,c,f] ----------------
__global__ __launch_bounds__(256) void gemm1_k(const float* __restrict__ x,
                                               const float* __restrict__ Whw,
                                               float* __restrict__ Wh) {
  const int h = blockIdx.x;          // head = 64-col tile
  const int row0 = blockIdx.y * 64;
  const int tid = threadIdx.x;
  __shared__ float As[32][68];       // [k][m], padded so float4 rows stay 16B-aligned
  __shared__ float Bs[32][64];       // [k][n]
  const int tx = tid & 15, ty = tid >> 4;
  float acc[4][4] = {};
  for (int k0 = 0; k0 < NFEAT; k0 += 32) {
    {
      int kk = tid & 31, m0 = (tid >> 5) * 8;
#pragma unroll
      for (int r = 0; r < 8; ++r)
        As[kk][m0 + r] = x[(size_t)(row0 + m0 + r) * NFEAT + k0 + kk];
    }
    {
      int f = tid & 63, c0 = tid >> 6;
#pragma unroll
      for (int r = 0; r < 8; ++r)
        Bs[c0 + r * 4][f] = Whw[(size_t)h * NFEAT * NHID + (size_t)(k0 + c0 + r * 4) * NHID + f];
    }
    __syncthreads();
#pragma unroll
    for (int kk = 0; kk < 32; ++kk) {
      float4 a4 = *reinterpret_cast<const float4*>(&As[kk][ty * 4]);
      float4 b4 = *reinterpret_cast<const float4*>(&Bs[kk][tx * 4]);
      float a[4] = {a4.x, a4.y, a4.z, a4.w};
      float b[4] = {b4.x, b4.y, b4.z, b4.w};
#pragma unroll
      for (int q = 0; q < 4; ++q)
#pragma unroll
        for (int p = 0; p < 4; ++p) acc[q][p] += a[q] * b[p];
    }
    __syncthreads();
  }
#pragma unroll
  for (int q = 0; q < 4; ++q) {
    float4 v = make_float4(acc[q][0], acc[q][1], acc[q][2], acc[q][3]);
    *reinterpret_cast<float4*>(&Wh[(size_t)(row0 + ty * 4 + q) * NFEAT + h * NHID + tx * 4]) = v;
  }
}

// ---------------- GEMM2: Wh2 = H @ W_out  ([8192,512]x[512,40]) ----------------
__global__ __launch_bounds__(256) void gemm2_k(const float* __restrict__ H,
                                               const float* __restrict__ Wout,
                                               float* __restrict__ Wh2) {
  const int row0 = blockIdx.x * 64;
  const int tid = threadIdx.x;
  __shared__ float As[32][68];
  __shared__ float Bs[32][40];
  const int m = tid >> 2;           // 0..63
  const int n0 = (tid & 3) * 10;    // 0,10,20,30
  float acc[10] = {};
  for (int k0 = 0; k0 < NFEAT; k0 += 32) {
    {
      int kk = tid & 31, m0 = (tid >> 5) * 8;
#pragma unroll
      for (int r = 0; r < 8; ++r)
        As[kk][m0 + r] = H[(size_t)(row0 + m0 + r) * NFEAT + k0 + kk];
    }
    {
#pragma unroll
      for (int r = 0; r < 5; ++r) {
        int idx = tid + r * 256;
        int c = idx / 40, n = idx - c * 40;
        Bs[c][n] = Wout[(size_t)(k0 + c) * NCLASS + n];
      }
    }
    __syncthreads();
#pragma unroll
    for (int kk = 0; kk < 32; ++kk) {
      float a = As[kk][m];
#pragma unroll
      for (int q = 0; q < 10; ++q) acc[q] += a * Bs[kk][n0 + q];
    }
    __syncthreads();
  }
#pragma unroll
  for (int q = 0; q < 10; ++q) Wh2[(size_t)(row0 + m) * NCLASS + n0 + q] = acc[q];
}

// ---------------- f1/f2 per (head,row): one wave per row ----------------
__global__ __launch_bounds__(256) void fvec1_k(const float* __restrict__ Wh,
                                               const float* __restrict__ a_heads,
                                               float* __restrict__ f1,
                                               float* __restrict__ f2) {
  int w = blockIdx.x * 4 + (threadIdx.x >> 6);
  int lane = threadIdx.x & 63;
  int head = w & 7, i = w >> 3;
  float wv = Wh[(size_t)i * NFEAT + head * NHID + lane];
  float p1 = wv * a_heads[head * 2 * NHID + lane];
  float p2 = wv * a_heads[head * 2 * NHID + NHID + lane];
#pragma unroll
  for (int m = 32; m; m >>= 1) { p1 += __shfl_xor(p1, m, 64); p2 += __shfl_xor(p2, m, 64); }
  if (lane == 0) { f1[head * N_NODES + i] = p1; f2[head * N_NODES + i] = p2; }
}

__global__ __launch_bounds__(256) void fvec2_k(const float* __restrict__ Wh2,
                                               const float* __restrict__ a_out,
                                               float* __restrict__ f1b,
                                               float* __restrict__ f2b) {
  int i = blockIdx.x * 4 + (threadIdx.x >> 6);
  int lane = threadIdx.x & 63;
  float p1 = 0.f, p2 = 0.f;
  if (lane < NCLASS) {
    float wv = Wh2[(size_t)i * NCLASS + lane];
    p1 = wv * a_out[lane];
    p2 = wv * a_out[NCLASS + lane];
  }
#pragma unroll
  for (int m = 32; m; m >>= 1) { p1 += __shfl_xor(p1, m, 64); p2 += __shfl_xor(p2, m, 64); }
  if (lane == 0) { f1b[i] = p1; f2b[i] = p2; }
}

// ---------------- max over a segment of 8192 ----------------
__global__ __launch_bounds__(1024) void maxk_k(const float* __restrict__ v, float* __restrict__ M) {
  int base = blockIdx.x * N_NODES;
  float m = -INFINITY;
  for (int i = threadIdx.x; i < N_NODES; i += 1024) m = fmaxf(m, v[base + i]);
  __shared__ float red[1024];
  red[threadIdx.x] = m;
  __syncthreads();
  for (int off = 512; off; off >>= 1) {
    if ((int)threadIdx.x < off) red[threadIdx.x] = fmaxf(red[threadIdx.x], red[threadIdx.x + off]);
    __syncthreads();
  }
  if (threadIdx.x == 0) M[blockIdx.x] = red[0];
}

// ---------------- column sums (uniform-fallback means; stored as SUMS) ----------------
__global__ __launch_bounds__(512) void mean1_k(const float* __restrict__ Wh, float* __restrict__ meanS) {
  int head = blockIdx.y;
  int r0 = blockIdx.x * 512;
  int t = threadIdx.x;
  int f = t & 63, rl = t >> 6;   // rl 0..7
  float acc = 0.f;
  for (int s = 0; s < 64; ++s) {
    int i = r0 + rl + s * 8;
    acc += Wh[(size_t)i * NFEAT + head * NHID + f];
  }
  __shared__ float red[512];
  red[t] = acc;
  __syncthreads();
  for (int off = 256; off >= 64; off >>= 1) {
    if (t < off) red[t] += red[t + off];
    __syncthreads();
  }
  if (t < 64) atomicAdd(&meanS[head * NHID + t], red[t]);
}

__global__ __launch_bounds__(256) void mean2_k(const float* __restrict__ Wh2, float* __restrict__ meanS2) {
  int n = blockIdx.x;
  float acc = 0.f;
  for (int i = threadIdx.x; i < N_NODES; i += 256) acc += Wh2[(size_t)i * NCLASS + n];
  __shared__ float red[256];
  red[threadIdx.x] = acc;
  __syncthreads();
  for (int off = 128; off; off >>= 1) {
    if ((int)threadIdx.x < off) red[threadIdx.x] += red[threadIdx.x + off];
    __syncthreads();
  }
  if (threadIdx.x == 0) meanS2[n] = red[0];
}

// ---------------- in-LDS bitonic sort of 8192 (key=f2 asc, payload=orig idx) ----------------
__global__ __launch_bounds__(1024) void sort_k(const float* __restrict__ f2,
                                               const float* __restrict__ M,
                                               float* __restrict__ f2s,
                                               int* __restrict__ idxs,
                                               float* __restrict__ g) {
  int base = blockIdx.x * N_NODES;
  __shared__ float sk[N_NODES];
  __shared__ int sv[N_NODES];
  for (int i = threadIdx.x; i < N_NODES; i += 1024) { sk[i] = f2[base + i]; sv[i] = i; }
  __syncthreads();
  for (int k = 2; k <= N_NODES; k <<= 1) {
    for (int j = k >> 1; j > 0; j >>= 1) {
      for (int p = threadIdx.x; p < N_NODES / 2; p += 1024) {
        int i = ((p & ~(j - 1)) << 1) | (p & (j - 1));
        int l = i | j;
        bool up = ((i & k) == 0);
        float ka = sk[i], kb = sk[l];
        bool sw = up ? (ka > kb) : (ka < kb);
        if (sw) {
          sk[i] = kb; sk[l] = ka;
          int va = sv[i]; sv[i] = sv[l]; sv[l] = va;
        }
      }
      __syncthreads();
    }
  }
  float Mh = M[blockIdx.x];
  for (int i = threadIdx.x; i < N_NODES; i += 1024) {
    float v = sk[i];
    f2s[base + i] = v;
    idxs[base + i] = sv[i];
    g[base + i] = expf(v - Mh);
  }
}

// ---------------- suffix scan phase A: per-chunk local suffix sums ----------------
template <int F, int LD, int COLSTEP>
__global__ __launch_bounds__(64) void scanA_k(const float* __restrict__ Wh,
                                              const float* __restrict__ g,
                                              const int* __restrict__ idxs,
                                              float* __restrict__ S,
                                              float* __restrict__ D,
                                              float* __restrict__ T,
                                              float* __restrict__ Td) {
  int head = blockIdx.y, chunk = blockIdx.x;
  int lane = threadIdx.x;
  int base = head * N_NODES;
  float acc = 0.f, accD = 0.f;
  for (int kk = CHUNK - 1; kk >= 0; --kk) {
    int k = chunk * CHUNK + kk;
    float gk = g[base + k];
    int j = idxs[base + k];
    float w = (lane < F) ? Wh[(size_t)j * LD + head * COLSTEP + lane] : 0.f;
    acc += gk * w;
    accD += gk;
    if (lane < F) S[(size_t)(base + k) * F + lane] = acc;
    if (lane == 0) D[base + k] = accD;
  }
  if (lane < F) T[(size_t)(head * NCHUNK + chunk) * F + lane] = acc;
  if (lane == 0) Td[head * NCHUNK + chunk] = accD;
}

// ---------------- suffix scan phase B: chunk totals -> inclusive suffix totals ----------------
template <int F>
__global__ __launch_bounds__(64) void scanB_k(float* __restrict__ T, float* __restrict__ Td) {
  int head = blockIdx.x;
  int lane = threadIdx.x;
  for (int c = NCHUNK - 2; c >= 0; --c) {
    if (lane < F) T[(size_t)(head * NCHUNK + c) * F + lane] += T[(size_t)(head * NCHUNK + c + 1) * F + lane];
    if (lane == 0) Td[head * NCHUNK + c] += Td[head * NCHUNK + c + 1];
  }
}

// ---------------- layer-1 queries: binary search + gather + elu ----------------
__global__ __launch_bounds__(256) void query1_k(const float* __restrict__ f1,
                                                const float* __restrict__ f2s,
                                                const float* __restrict__ S,
                                                const float* __restrict__ D,
                                                const float* __restrict__ T,
                                                const float* __restrict__ Td,
                                                const float* __restrict__ meanS,
                                                float* __restrict__ H) {
  int w = blockIdx.x * 4 + (threadIdx.x >> 6);
  int lane = threadIdx.x & 63;
  int head = w & 7, i = w >> 3;
  int base = head * N_NODES;
  float t = f1[base + i];
  int lo = 0, hi = N_NODES;
  while (lo < hi) {
    int mid = (lo + hi) >> 1;
    if (t + f2s[base + mid] > 0.f) hi = mid; else lo = mid + 1;
  }
  float val;
  if (lo == N_NODES) {
    val = meanS[head * NHID + lane] * (1.f / N_NODES);
  } else {
    int c = lo >> 6;
    float off  = (c + 1 < NCHUNK) ? T[(size_t)(head * NCHUNK + c + 1) * NHID + lane] : 0.f;
    float offD = (c + 1 < NCHUNK) ? Td[head * NCHUNK + c + 1] : 0.f;
    val = (S[(size_t)(base + lo) * NHID + lane] + off) / (D[base + lo] + offD);
  }
  H[(size_t)i * NFEAT + head * NHID + lane] = (val > 0.f) ? val : expm1f(val);
}

// ---------------- layer-2 queries + elu + log_softmax ----------------
__global__ __launch_bounds__(256) void final_k(const float* __restrict__ f1b,
                                               const float* __restrict__ f2bs,
                                               const float* __restrict__ S2,
                                               const float* __restrict__ D2,
                                               const float* __restrict__ T2,
                                               const float* __restrict__ Td2,
                                               const float* __restrict__ meanS2,
                                               float* __restrict__ out) {
  int i = blockIdx.x * 4 + (threadIdx.x >> 6);
  int lane = threadIdx.x & 63;
  float t = f1b[i];
  int lo = 0, hi = N_NODES;
  while (lo < hi) {
    int mid = (lo + hi) >> 1;
    if (t + f2bs[mid] > 0.f) hi = mid; else lo = mid + 1;
  }
  float o;
  if (lane < NCLASS) {
    float val;
    if (lo == N_NODES) {
      val = meanS2[lane] * (1.f / N_NODES);
    } else {
      int c = lo >> 6;
      float off  = (c + 1 < NCHUNK) ? T2[(size_t)(c + 1) * NCLASS + lane] : 0.f;
      float offD = (c + 1 < NCHUNK) ? Td2[c + 1] : 0.f;
      val = (S2[(size_t)lo * NCLASS + lane] + off) / (D2[lo] + offD);
    }
    o = (val > 0.f) ? val : expm1f(val);
  } else {
    o = -INFINITY;
  }
  float m = o;
#pragma unroll
  for (int msk = 32; msk; msk >>= 1) m = fmaxf(m, __shfl_xor(m, msk, 64));
  float e = (lane < NCLASS) ? expf(o - m) : 0.f;
#pragma unroll
  for (int msk = 32; msk; msk >>= 1) e += __shfl_xor(e, msk, 64);
  if (lane < NCLASS) out[(size_t)i * NCLASS + lane] = o - m - logf(e);
}

extern "C" void kernel_launch(void* const* d_in, const int* in_sizes, int n_in,
                              void* d_out, int out_size, void* d_ws, size_t ws_size,
                              hipStream_t stream) {
  const float* x       = (const float*)d_in[0];
  // d_in[1] = adj: unused by the reference math
  const float* W_heads = (const float*)d_in[2];
  const float* a_heads = (const float*)d_in[3];
  const float* W_out   = (const float*)d_in[4];
  const float* a_out   = (const float*)d_in[5];
  float* out = (float*)d_out;

  float* ws = (float*)d_ws;
  size_t o = 0;
  auto alloc = [&](size_t n) { float* p = ws + o; o += n; return p; };
  float* Wh     = alloc((size_t)N_NODES * NFEAT);        // 16 MB
  float* H      = alloc((size_t)N_NODES * NFEAT);        // 16 MB
  float* S1     = alloc((size_t)NHEADS * N_NODES * NHID);// 16 MB
  float* f1     = alloc(NHEADS * N_NODES);
  float* f2     = alloc(NHEADS * N_NODES);
  float* f2s    = alloc(NHEADS * N_NODES);
  int*   idxs   = (int*)alloc(NHEADS * N_NODES);
  float* g1     = alloc(NHEADS * N_NODES);
  float* D1     = alloc(NHEADS * N_NODES);
  float* T1     = alloc(NHEADS * NCHUNK * NHID);
  float* Td1    = alloc(NHEADS * NCHUNK);
  float* M1     = alloc(8);
  float* meanS1 = alloc(NHEADS * NHID);
  float* Wh2    = alloc((size_t)N_NODES * NCLASS);
  float* S2     = alloc((size_t)N_NODES * NCLASS);
  float* f1b    = alloc(N_NODES);
  float* f2b    = alloc(N_NODES);
  float* f2bs   = alloc(N_NODES);
  int*   idx2   = (int*)alloc(N_NODES);
  float* g2     = alloc(N_NODES);
  float* D2     = alloc(N_NODES);
  float* T2     = alloc(NCHUNK * NCLASS);
  float* Td2    = alloc(NCHUNK);
  float* M2     = alloc(8);
  float* meanS2 = alloc(64);

  hipMemsetAsync(meanS1, 0, NHEADS * NHID * sizeof(float), stream);

  // ---- layer 1 ----
  gemm1_k<<<dim3(8, 128), 256, 0, stream>>>(x, W_heads, Wh);
  fvec1_k<<<16384, 256, 0, stream>>>(Wh, a_heads, f1, f2);
  maxk_k<<<8, 1024, 0, stream>>>(f2, M1);
  mean1_k<<<dim3(16, 8), 512, 0, stream>>>(Wh, meanS1);
  sort_k<<<8, 1024, 0, stream>>>(f2, M1, f2s, idxs, g1);
  scanA_k<NHID, NFEAT, NHID><<<dim3(NCHUNK, NHEADS), 64, 0, stream>>>(Wh, g1, idxs, S1, D1, T1, Td1);
  scanB_k<NHID><<<NHEADS, 64, 0, stream>>>(T1, Td1);
  query1_k<<<16384, 256, 0, stream>>>(f1, f2s, S1, D1, T1, Td1, meanS1, H);

  // ---- layer 2 ----
  gemm2_k<<<128, 256, 0, stream>>>(H, W_out, Wh2);
  fvec2_k<<<2048, 256, 0, stream>>>(Wh2, a_out, f1b, f2b);
  maxk_k<<<1, 1024, 0, stream>>>(f2b, M2);
  mean2_k<<<NCLASS, 256, 0, stream>>>(Wh2, meanS2);
  sort_k<<<1, 1024, 0, stream>>>(f2b, M2, f2bs, idx2, g2);
  scanA_k<NCLASS, NCLASS, 0><<<dim3(NCHUNK, 1), 64, 0, stream>>>(Wh2, g2, idx2, S2, D2, T2, Td2);
  scanB_k<NCLASS><<<1, 64, 0, stream>>>(T2, Td2);
  final_k<<<2048, 256, 0, stream>>>(f1b, f2bs, S2, D2, T2, Td2, meanS2, out);
}

// Round 2
// 584.377 us; speedup vs baseline: 1.3878x; 1.3878x over previous
//
#include <hip/hip_runtime.h>
#include <math.h>

#define N_NODES 8192
#define NFEAT 512
#define NHID 64
#define NHEADS 8
#define NCLASS 40
#define NCHUNK 128
#define CHUNK 64
#define NB 4096

// ---------------- GEMM1 fused: Wh = x@W per head, + f1/f2 dots + column sums ----------------
__global__ __launch_bounds__(256) void gemm1_k(const float* __restrict__ x,
                                               const float* __restrict__ Whw,
                                               const float* __restrict__ a_heads,
                                               float* __restrict__ Wh,
                                               float* __restrict__ f1,
                                               float* __restrict__ f2,
                                               float* __restrict__ meanS) {
  const int head = blockIdx.x;
  const int row0 = blockIdx.y * 64;
  const int tid = threadIdx.x;
  __shared__ float As[32][68];
  __shared__ float Bs[32][64];
  const int tx = tid & 15, ty = tid >> 4;
  float acc[4][4] = {};
  for (int k0 = 0; k0 < NFEAT; k0 += 32) {
    {
      int kk = tid & 31, m0 = (tid >> 5) * 8;
#pragma unroll
      for (int r = 0; r < 8; ++r)
        As[kk][m0 + r] = x[(size_t)(row0 + m0 + r) * NFEAT + k0 + kk];
    }
    {
      int f = tid & 63, c0 = tid >> 6;
#pragma unroll
      for (int r = 0; r < 8; ++r)
        Bs[c0 + r * 4][f] = Whw[(size_t)head * NFEAT * NHID + (size_t)(k0 + c0 + r * 4) * NHID + f];
    }
    __syncthreads();
#pragma unroll
    for (int kk = 0; kk < 32; ++kk) {
      float4 a4 = *reinterpret_cast<const float4*>(&As[kk][ty * 4]);
      float4 b4 = *reinterpret_cast<const float4*>(&Bs[kk][tx * 4]);
      float a[4] = {a4.x, a4.y, a4.z, a4.w};
      float b[4] = {b4.x, b4.y, b4.z, b4.w};
#pragma unroll
      for (int q = 0; q < 4; ++q)
#pragma unroll
        for (int p = 0; p < 4; ++p) acc[q][p] += a[q] * b[p];
    }
    __syncthreads();
  }
  // store Wh tile
#pragma unroll
  for (int q = 0; q < 4; ++q) {
    float4 v = make_float4(acc[q][0], acc[q][1], acc[q][2], acc[q][3]);
    *reinterpret_cast<float4*>(&Wh[(size_t)(row0 + ty * 4 + q) * NFEAT + head * NHID + tx * 4]) = v;
  }
  // fused f1/f2: dot each row with a1/a2, reduce across tx (16 lanes, bits 0-3)
  const float* ah = a_heads + head * 2 * NHID;
  float a1v[4], a2v[4];
#pragma unroll
  for (int p = 0; p < 4; ++p) { a1v[p] = ah[tx * 4 + p]; a2v[p] = ah[NHID + tx * 4 + p]; }
#pragma unroll
  for (int q = 0; q < 4; ++q) {
    float s1 = 0.f, s2 = 0.f;
#pragma unroll
    for (int p = 0; p < 4; ++p) { s1 += acc[q][p] * a1v[p]; s2 += acc[q][p] * a2v[p]; }
#pragma unroll
    for (int m = 1; m < 16; m <<= 1) { s1 += __shfl_xor(s1, m, 64); s2 += __shfl_xor(s2, m, 64); }
    if (tx == 0) {
      int r = row0 + ty * 4 + q;
      f1[(head << 13) + r] = s1;
      f2[(head << 13) + r] = s2;
    }
  }
  // fused column sums (for uniform fallback), staged through LDS
  __syncthreads();
  float* colp = &As[0][0];  // reuse as [16][64]
#pragma unroll
  for (int p = 0; p < 4; ++p)
    colp[ty * 64 + tx * 4 + p] = acc[0][p] + acc[1][p] + acc[2][p] + acc[3][p];
  __syncthreads();
  if (tid < 64) {
    float s = 0.f;
#pragma unroll
    for (int yy = 0; yy < 16; ++yy) s += colp[yy * 64 + tid];
    atomicAdd(&meanS[head * NHID + tid], s);
  }
}

// ---------------- GEMM2 fused: Wh2 = H @ W_out + f1b/f2b + column sums ----------------
__global__ __launch_bounds__(256) void gemm2_k(const float* __restrict__ H,
                                               const float* __restrict__ Wout,
                                               const float* __restrict__ a_out,
                                               float* __restrict__ Wh2,
                                               float* __restrict__ f1b,
                                               float* __restrict__ f2b,
                                               float* __restrict__ meanS2) {
  const int row0 = blockIdx.x * 64;
  const int tid = threadIdx.x;
  __shared__ float As[32][68];
  __shared__ float Bs[32][40];
  __shared__ float cs[NCLASS];
  if (tid < NCLASS) cs[tid] = 0.f;
  const int m = tid >> 2;
  const int n0 = (tid & 3) * 10;
  float acc[10] = {};
  for (int k0 = 0; k0 < NFEAT; k0 += 32) {
    {
      int kk = tid & 31, m0 = (tid >> 5) * 8;
#pragma unroll
      for (int r = 0; r < 8; ++r)
        As[kk][m0 + r] = H[(size_t)(row0 + m0 + r) * NFEAT + k0 + kk];
    }
    {
#pragma unroll
      for (int r = 0; r < 5; ++r) {
        int idx = tid + r * 256;
        int c = idx / 40, n = idx - c * 40;
        Bs[c][n] = Wout[(size_t)(k0 + c) * NCLASS + n];
      }
    }
    __syncthreads();
#pragma unroll
    for (int kk = 0; kk < 32; ++kk) {
      float a = As[kk][m];
#pragma unroll
      for (int q = 0; q < 10; ++q) acc[q] += a * Bs[kk][n0 + q];
    }
    __syncthreads();
  }
#pragma unroll
  for (int q = 0; q < 10; ++q) Wh2[(size_t)(row0 + m) * NCLASS + n0 + q] = acc[q];
  // fused f1b/f2b (reduce across the 4 lanes sharing a row: bits 0-1)
  float p1 = 0.f, p2 = 0.f;
#pragma unroll
  for (int q = 0; q < 10; ++q) {
    p1 += acc[q] * a_out[n0 + q];
    p2 += acc[q] * a_out[NCLASS + n0 + q];
  }
  p1 += __shfl_xor(p1, 1, 64); p1 += __shfl_xor(p1, 2, 64);
  p2 += __shfl_xor(p2, 1, 64); p2 += __shfl_xor(p2, 2, 64);
  if ((tid & 3) == 0) { f1b[row0 + m] = p1; f2b[row0 + m] = p2; }
  // fused column sums
  __syncthreads();
#pragma unroll
  for (int q = 0; q < 10; ++q) atomicAdd(&cs[n0 + q], acc[q]);
  __syncthreads();
  if (tid < NCLASS) atomicAdd(&meanS2[tid], cs[tid]);
}

// ---------------- per-head min/max of f2 -> bucket range + softmax max ----------------
__global__ __launch_bounds__(1024) void minmax_k(const float* __restrict__ f2, float4* __restrict__ rng) {
  int head = blockIdx.x, tid = threadIdx.x;
  const float* p = f2 + (head << 13);
  float lo = INFINITY, hi = -INFINITY;
  for (int i = tid; i < N_NODES; i += 1024) { float v = p[i]; lo = fminf(lo, v); hi = fmaxf(hi, v); }
  __shared__ float slo[1024], shi[1024];
  slo[tid] = lo; shi[tid] = hi;
  __syncthreads();
  for (int off = 512; off; off >>= 1) {
    if (tid < off) { slo[tid] = fminf(slo[tid], slo[tid + off]); shi[tid] = fmaxf(shi[tid], shi[tid + off]); }
    __syncthreads();
  }
  if (tid == 0) {
    float l = slo[0], h = shi[0];
    float w = fmaxf(h - l, 1e-30f);
    rng[head] = make_float4(l, (float)NB / w, h, 0.f);
  }
}

// ---------------- bucket histogram ----------------
__global__ __launch_bounds__(256) void hist_k(const float* __restrict__ f2, const float4* __restrict__ rng,
                                              int* __restrict__ hist) {
  int gid = blockIdx.x * 256 + threadIdx.x;
  int head = gid >> 13;
  float v = f2[gid];
  float4 rg = rng[head];
  float u = fminf(fmaxf((v - rg.x) * rg.y, 0.f), (float)(NB - 1));
  atomicAdd(&hist[head * NB + (int)u], 1);
}

// ---------------- per-head exclusive prefix over NB buckets ----------------
__global__ __launch_bounds__(1024) void prefix_k(const int* __restrict__ hist, int* __restrict__ bs) {
  __shared__ int sb[NB];
  int head = blockIdx.x, tid = threadIdx.x;
#pragma unroll
  for (int r = 0; r < NB / 1024; ++r) sb[tid + r * 1024] = hist[head * NB + tid + r * 1024];
  __syncthreads();
  for (int st = 1; st < NB; st <<= 1) {
    int v[NB / 1024];
#pragma unroll
    for (int r = 0; r < NB / 1024; ++r) { int i = tid + r * 1024; v[r] = (i >= st) ? sb[i - st] : 0; }
    __syncthreads();
#pragma unroll
    for (int r = 0; r < NB / 1024; ++r) sb[tid + r * 1024] += v[r];
    __syncthreads();
  }
#pragma unroll
  for (int r = 0; r < NB / 1024; ++r) {
    int b = tid + r * 1024;
    bs[head * (NB + 1) + b] = b ? sb[b - 1] : 0;
  }
  if (tid == 0) bs[head * (NB + 1) + NB] = sb[NB - 1];
}

// ---------------- bucket scatter: idx/f2/g in bucket-monotone order ----------------
__global__ __launch_bounds__(256) void scat_k(const float* __restrict__ f2, const float4* __restrict__ rng,
                                              const int* __restrict__ bs, int* __restrict__ cnt,
                                              int* __restrict__ idxs, float* __restrict__ f2s,
                                              float* __restrict__ g) {
  int gid = blockIdx.x * 256 + threadIdx.x;
  int head = gid >> 13, i = gid & 8191;
  float v = f2[gid];
  float4 rg = rng[head];
  float u = fminf(fmaxf((v - rg.x) * rg.y, 0.f), (float)(NB - 1));
  int b = (int)u;
  int pos = bs[head * (NB + 1) + b] + atomicAdd(&cnt[head * NB + b], 1);
  int base = head << 13;
  idxs[base + pos] = i;
  f2s[base + pos] = v;
  g[base + pos] = expf(v - rg.z);
}

// ---------------- suffix scan phase A: per-chunk local suffix sums ----------------
template <int F, int LD, int COLSTEP>
__global__ __launch_bounds__(64) void scanA_k(const float* __restrict__ Wh,
                                              const float* __restrict__ g,
                                              const int* __restrict__ idxs,
                                              float* __restrict__ S,
                                              float* __restrict__ D,
                                              float* __restrict__ T,
                                              float* __restrict__ Td) {
  int head = blockIdx.y, chunk = blockIdx.x;
  int lane = threadIdx.x;
  int base = head << 13;
  int kbase = base + chunk * CHUNK;
  int myj = idxs[kbase + lane];
  float myg = g[kbase + lane];
  float acc = 0.f, accD = 0.f;
#pragma unroll
  for (int kk = CHUNK - 1; kk >= 0; --kk) {
    int j = __shfl(myj, kk, 64);
    float gk = __shfl(myg, kk, 64);
    float w = (lane < F) ? Wh[(size_t)j * LD + head * COLSTEP + lane] : 0.f;
    acc += gk * w;
    accD += gk;
    if (lane < F) S[(size_t)(kbase + kk) * F + lane] = acc;
    if (lane == 0) D[kbase + kk] = accD;
  }
  if (lane < F) T[(size_t)(head * NCHUNK + chunk) * F + lane] = acc;
  if (lane == 0) Td[head * NCHUNK + chunk] = accD;
}

// ---------------- suffix scan phase B: parallel LDS Hillis-Steele over chunk totals ----------------
template <int F>
__global__ __launch_bounds__(1024) void scanB_k(float* __restrict__ T, float* __restrict__ Td) {
  __shared__ float s[NCHUNK * F];
  __shared__ float td[NCHUNK];
  int head = blockIdx.x;
  int tid = threadIdx.x, slot = tid >> 6, lane = tid & 63;
#pragma unroll
  for (int r = 0; r < 8; ++r) {
    int c = r * 16 + slot;
    if (lane < F) s[c * F + lane] = T[(size_t)(head * NCHUNK + c) * F + lane];
  }
  if (tid < NCHUNK) td[tid] = Td[head * NCHUNK + tid];
  __syncthreads();
  for (int st = 1; st < NCHUNK; st <<= 1) {
    float v[8];
    float tv = 0.f;
#pragma unroll
    for (int r = 0; r < 8; ++r) {
      int c = r * 16 + slot;
      v[r] = (lane < F && c + st < NCHUNK) ? s[(c + st) * F + lane] : 0.f;
    }
    if (tid < NCHUNK && tid + st < NCHUNK) tv = td[tid + st];
    __syncthreads();
#pragma unroll
    for (int r = 0; r < 8; ++r) {
      int c = r * 16 + slot;
      if (lane < F) s[c * F + lane] += v[r];
    }
    if (tid < NCHUNK) td[tid] += tv;
    __syncthreads();
  }
#pragma unroll
  for (int r = 0; r < 8; ++r) {
    int c = r * 16 + slot;
    if (lane < F) T[(size_t)(head * NCHUNK + c) * F + lane] = s[c * F + lane];
  }
  if (tid < NCHUNK) Td[head * NCHUNK + tid] = td[tid];
}

// ---------------- layer-1 queries: bucket lookup + exact boundary scan + elu ----------------
__global__ __launch_bounds__(256) void query1_k(const float* __restrict__ f1,
                                                const float* __restrict__ f2s,
                                                const int* __restrict__ idxs,
                                                const float* __restrict__ Wh,
                                                const float* __restrict__ S,
                                                const float* __restrict__ D,
                                                const float* __restrict__ T,
                                                const float* __restrict__ Td,
                                                const float4* __restrict__ rng,
                                                const int* __restrict__ bs,
                                                const float* __restrict__ meanS,
                                                float* __restrict__ H) {
  int w = blockIdx.x * 4 + (threadIdx.x >> 6);
  int lane = threadIdx.x & 63;
  int head = w & 7, i = w >> 3, base = head << 13;
  float t = f1[base + i];
  float4 rg = rng[head];
  float u = fminf(fmaxf((-t - rg.x) * rg.y, 0.f), (float)(NB - 1));
  int B0 = (int)u;
  int p0 = bs[head * (NB + 1) + B0], p1 = bs[head * (NB + 1) + B0 + 1];
  float num = 0.f, den = 0.f;
  int cnt = N_NODES - p1;
  if (p1 < N_NODES) {
    int c = p1 >> 6;
    num = S[(size_t)(base + p1) * NHID + lane] +
          ((c + 1 < NCHUNK) ? T[(size_t)(head * NCHUNK + c + 1) * NHID + lane] : 0.f);
    den = D[base + p1] + ((c + 1 < NCHUNK) ? Td[head * NCHUNK + c + 1] : 0.f);
  }
  for (int p = p0; p < p1; ++p) {
    float v = f2s[base + p];
    if (t + v > 0.f) {  // exact reference predicate
      int j = idxs[base + p];
      float gk = expf(v - rg.z);
      num += gk * Wh[(size_t)j * NFEAT + head * NHID + lane];
      den += gk;
      ++cnt;
    }
  }
  float val = cnt ? num / den : meanS[head * NHID + lane] * (1.f / N_NODES);
  H[(size_t)i * NFEAT + head * NHID + lane] = (val > 0.f) ? val : expm1f(val);
}

// ---------------- layer-2 queries + elu + log_softmax ----------------
__global__ __launch_bounds__(256) void final_k(const float* __restrict__ f1b,
                                               const float* __restrict__ f2bs,
                                               const int* __restrict__ idx2,
                                               const float* __restrict__ Wh2,
                                               const float* __restrict__ S2,
                                               const float* __restrict__ D2,
                                               const float* __restrict__ T2,
                                               const float* __restrict__ Td2,
                                               const float4* __restrict__ rng2,
                                               const int* __restrict__ bs2,
                                               const float* __restrict__ meanS2,
                                               float* __restrict__ out) {
  int i = blockIdx.x * 4 + (threadIdx.x >> 6);
  int lane = threadIdx.x & 63;
  float t = f1b[i];
  float4 rg = rng2[0];
  float u = fminf(fmaxf((-t - rg.x) * rg.y, 0.f), (float)(NB - 1));
  int B0 = (int)u;
  int p0 = bs2[B0], p1 = bs2[B0 + 1];
  float num = 0.f, den = 0.f;
  int cnt = N_NODES - p1;
  if (p1 < N_NODES) {
    int c = p1 >> 6;
    num = (lane < NCLASS) ? (S2[(size_t)p1 * NCLASS + lane] +
                             ((c + 1 < NCHUNK) ? T2[(size_t)(c + 1) * NCLASS + lane] : 0.f))
                          : 0.f;
    den = D2[p1] + ((c + 1 < NCHUNK) ? Td2[c + 1] : 0.f);
  }
  for (int p = p0; p < p1; ++p) {
    float v = f2bs[p];
    if (t + v > 0.f) {
      int j = idx2[p];
      float gk = expf(v - rg.z);
      if (lane < NCLASS) num += gk * Wh2[(size_t)j * NCLASS + lane];
      den += gk;
      ++cnt;
    }
  }
  float o;
  if (lane < NCLASS) {
    float val = cnt ? num / den : meanS2[lane] * (1.f / N_NODES);
    o = (val > 0.f) ? val : expm1f(val);
  } else {
    o = -INFINITY;
  }
  float m = o;
#pragma unroll
  for (int msk = 32; msk; msk >>= 1) m = fmaxf(m, __shfl_xor(m, msk, 64));
  float e = (lane < NCLASS) ? expf(o - m) : 0.f;
#pragma unroll
  for (int msk = 32; msk; msk >>= 1) e += __shfl_xor(e, msk, 64);
  if (lane < NCLASS) out[(size_t)i * NCLASS + lane] = o - m - logf(e);
}

extern "C" void kernel_launch(void* const* d_in, const int* in_sizes, int n_in,
                              void* d_out, int out_size, void* d_ws, size_t ws_size,
                              hipStream_t stream) {
  const float* x       = (const float*)d_in[0];
  const float* W_heads = (const float*)d_in[2];
  const float* a_heads = (const float*)d_in[3];
  const float* W_out   = (const float*)d_in[4];
  const float* a_out   = (const float*)d_in[5];
  float* out = (float*)d_out;

  float* ws = (float*)d_ws;
  size_t o = 0;
  auto alloc = [&](size_t n) { float* p = ws + o; o += (n + 3) & ~(size_t)3; return p; };
  float*  Wh     = alloc((size_t)N_NODES * NFEAT);
  float*  H      = alloc((size_t)N_NODES * NFEAT);
  float*  S1     = alloc((size_t)NHEADS * N_NODES * NHID);
  float*  f1     = alloc(NHEADS * N_NODES);
  float*  f2     = alloc(NHEADS * N_NODES);
  float*  f2s    = alloc(NHEADS * N_NODES);
  int*    idxs   = (int*)alloc(NHEADS * N_NODES);
  float*  g1     = alloc(NHEADS * N_NODES);
  float*  D1     = alloc(NHEADS * N_NODES);
  float*  T1     = alloc(NHEADS * NCHUNK * NHID);
  float*  Td1    = alloc(NHEADS * NCHUNK);
  float4* rng1   = (float4*)alloc(NHEADS * 4);
  int*    bst1   = (int*)alloc(NHEADS * (NB + 1));
  float*  Wh2    = alloc((size_t)N_NODES * NCLASS);
  float*  S2     = alloc((size_t)N_NODES * NCLASS);
  float*  f1b    = alloc(N_NODES);
  float*  f2b    = alloc(N_NODES);
  float*  f2bs   = alloc(N_NODES);
  int*    idx2   = (int*)alloc(N_NODES);
  float*  g2     = alloc(N_NODES);
  float*  D2     = alloc(N_NODES);
  float*  T2     = alloc(NCHUNK * NCLASS);
  float*  Td2    = alloc(NCHUNK);
  float4* rng2   = (float4*)alloc(4);
  int*    bst2   = (int*)alloc(NB + 1);
  // ---- contiguous zero region ----
  float*  zbase  = ws + o;
  int*    hist1  = (int*)alloc((size_t)NHEADS * NB);
  int*    cnt1   = (int*)alloc((size_t)NHEADS * NB);
  int*    hist2  = (int*)alloc(NB);
  int*    cnt2   = (int*)alloc(NB);
  float*  meanS1 = alloc(NHEADS * NHID);
  float*  meanS2 = alloc(64);
  size_t zbytes = (size_t)((ws + o) - zbase) * sizeof(float);
  hipMemsetAsync(zbase, 0, zbytes, stream);

  // ---- layer 1 ----
  gemm1_k<<<dim3(8, 128), 256, 0, stream>>>(x, W_heads, a_heads, Wh, f1, f2, meanS1);
  minmax_k<<<NHEADS, 1024, 0, stream>>>(f2, rng1);
  hist_k<<<(NHEADS * N_NODES) / 256, 256, 0, stream>>>(f2, rng1, hist1);
  prefix_k<<<NHEADS, 1024, 0, stream>>>(hist1, bst1);
  scat_k<<<(NHEADS * N_NODES) / 256, 256, 0, stream>>>(f2, rng1, bst1, cnt1, idxs, f2s, g1);
  scanA_k<NHID, NFEAT, NHID><<<dim3(NCHUNK, NHEADS), 64, 0, stream>>>(Wh, g1, idxs, S1, D1, T1, Td1);
  scanB_k<NHID><<<NHEADS, 1024, 0, stream>>>(T1, Td1);
  query1_k<<<16384, 256, 0, stream>>>(f1, f2s, idxs, Wh, S1, D1, T1, Td1, rng1, bst1, meanS1, H);

  // ---- layer 2 ----
  gemm2_k<<<128, 256, 0, stream>>>(H, W_out, a_out, Wh2, f1b, f2b, meanS2);
  minmax_k<<<1, 1024, 0, stream>>>(f2b, rng2);
  hist_k<<<N_NODES / 256, 256, 0, stream>>>(f2b, rng2, hist2);
  prefix_k<<<1, 1024, 0, stream>>>(hist2, bst2);
  scat_k<<<N_NODES / 256, 256, 0, stream>>>(f2b, rng2, bst2, cnt2, idx2, f2bs, g2);
  scanA_k<NCLASS, NCLASS, 0><<<dim3(NCHUNK, 1), 64, 0, stream>>>(Wh2, g2, idx2, S2, D2, T2, Td2);
  scanB_k<NCLASS><<<1, 1024, 0, stream>>>(T2, Td2);
  final_k<<<2048, 256, 0, stream>>>(f1b, f2bs, idx2, Wh2, S2, D2, T2, Td2, rng2, bst2, meanS2, out);
}

// Round 4
// 561.078 us; speedup vs baseline: 1.4455x; 1.0415x over previous
//
#include <hip/hip_runtime.h>
#include <math.h>

#define N_NODES 8192
#define NFEAT 512
#define NHID 64
#define NHEADS 8
#define NCLASS 40
#define NCHUNK 128
#define CHUNK 64
#define NB 4096

using bf16x8 = __attribute__((ext_vector_type(8))) short;
using f32x4 = __attribute__((ext_vector_type(4))) float;

// ---- helpers ----
__device__ __forceinline__ ushort f2b(float f) {  // fp32 -> bf16 RNE
  uint u = __builtin_bit_cast(uint, f);
  u += 0x7FFFu + ((u >> 16) & 1u);
  return (ushort)(u >> 16);
}
__device__ __forceinline__ float b2f(ushort h) {
  uint u = (uint)h << 16;
  return __builtin_bit_cast(float, u);
}
__device__ __forceinline__ uint encf(float f) {  // sortable-ascending uint
  uint u = __builtin_bit_cast(uint, f);
  return u ^ ((u >> 31) ? 0xFFFFFFFFu : 0x80000000u);
}
__device__ __forceinline__ float decf(uint u) {
  u ^= ((u >> 31) ? 0x80000000u : 0xFFFFFFFFu);
  return __builtin_bit_cast(float, u);
}
__device__ __forceinline__ float3 load_rng(const uint* mm, int head) {
  float h = decf(mm[head * 2]);        // max f2
  float l = decf(~mm[head * 2 + 1]);   // min f2 (stored as max of ~enc)
  float scale = (float)NB / fmaxf(h - l, 1e-30f);
  return make_float3(l, scale, h);
}
__device__ __forceinline__ int bucket_of(float v, float lo, float scale) {
  float u = fminf(fmaxf((v - lo) * scale, 0.f), (float)(NB - 1));
  return (int)u;
}

// ---------------- prep: split x and B' (=W transposed) into bf16 hi/lo planes ----------------
__global__ __launch_bounds__(256) void prep_k(const float* __restrict__ x,
                                              const float* __restrict__ W_heads,
                                              ushort* __restrict__ bth,
                                              ushort* __restrict__ btl,
                                              ushort* __restrict__ xh_,
                                              ushort* __restrict__ xl_) {
  int b = blockIdx.x, t = threadIdx.x;
  if (b < 1024) {
    // BT[n][c] = W_heads[h][c][f], n = h*64+f   (512x512), split hi/lo
    int gid = b * 256 + t;
    int n = gid >> 9, c = gid & 511;
    int h = n >> 6, f = n & 63;
    float w = W_heads[((size_t)h * NFEAT + c) * NHID + f];
    ushort hh = f2b(w);
    bth[gid] = hh;
    btl[gid] = f2b(w - b2f(hh));
  } else {
    // x split: 8 elements per thread
    int gid2 = (b - 1024) * 256 + t;  // 0..524287
    const float* src = x + (size_t)gid2 * 8;
    float4 v0 = *reinterpret_cast<const float4*>(src);
    float4 v1 = *reinterpret_cast<const float4*>(src + 4);
    float vv[8] = {v0.x, v0.y, v0.z, v0.w, v1.x, v1.y, v1.z, v1.w};
    uint uh[4], ul[4];
#pragma unroll
    for (int k = 0; k < 4; ++k) {
      ushort h0 = f2b(vv[2 * k]), h1 = f2b(vv[2 * k + 1]);
      ushort l0 = f2b(vv[2 * k] - b2f(h0)), l1 = f2b(vv[2 * k + 1] - b2f(h1));
      uh[k] = (uint)h0 | ((uint)h1 << 16);
      ul[k] = (uint)l0 | ((uint)l1 << 16);
    }
    *reinterpret_cast<uint4*>(xh_ + (size_t)gid2 * 8) = make_uint4(uh[0], uh[1], uh[2], uh[3]);
    *reinterpret_cast<uint4*>(xl_ + (size_t)gid2 * 8) = make_uint4(ul[0], ul[1], ul[2], ul[3]);
  }
}

// ---------------- GEMM1: Wh(fp32) = x @ B' via split-bf16 MFMA (3 terms), 128x128 tiles ----
// Fused epilogue: f1/f2 row dots, per-head f2 min/max, per-head column sums (meanS).
__global__ __launch_bounds__(256) void gemm1_k(const ushort* __restrict__ xh,
                                               const ushort* __restrict__ xl,
                                               const ushort* __restrict__ bth,
                                               const ushort* __restrict__ btl,
                                               const float* __restrict__ a_heads,
                                               float* __restrict__ Wh,
                                               float* __restrict__ f1,
                                               float* __restrict__ f2,
                                               float* __restrict__ meanS,
                                               uint* __restrict__ mm1) {
  const int row0 = blockIdx.x * 128, col0 = blockIdx.y * 128;
  const int tid = threadIdx.x;
  const int wave = tid >> 6, lane = tid & 63;
  const int wr = wave >> 1, wc = wave & 1;
  __shared__ ushort Ah[128 * 40], Al[128 * 40], Bh[128 * 40], Bl[128 * 40];
  __shared__ float cs[2][64];
  __shared__ uint lmax[2], lmin[2];
  if (tid < 2) { lmax[tid] = 0u; lmin[tid] = 0u; }
  if (tid < 128) cs[tid >> 6][tid & 63] = 0.f;
  f32x4 acc[4][4] = {};
  const int sr = tid >> 1, sh = (tid & 1) * 16;
  const int fr = lane & 15, quad = lane >> 4;
  for (int k0 = 0; k0 < NFEAT; k0 += 32) {
    {
      size_t aoff = (size_t)(row0 + sr) * NFEAT + k0 + sh;
      *reinterpret_cast<uint4*>(&Ah[sr * 40 + sh])     = *reinterpret_cast<const uint4*>(xh + aoff);
      *reinterpret_cast<uint4*>(&Ah[sr * 40 + sh + 8]) = *reinterpret_cast<const uint4*>(xh + aoff + 8);
      *reinterpret_cast<uint4*>(&Al[sr * 40 + sh])     = *reinterpret_cast<const uint4*>(xl + aoff);
      *reinterpret_cast<uint4*>(&Al[sr * 40 + sh + 8]) = *reinterpret_cast<const uint4*>(xl + aoff + 8);
      size_t boff = (size_t)(col0 + sr) * NFEAT + k0 + sh;
      *reinterpret_cast<uint4*>(&Bh[sr * 40 + sh])     = *reinterpret_cast<const uint4*>(bth + boff);
      *reinterpret_cast<uint4*>(&Bh[sr * 40 + sh + 8]) = *reinterpret_cast<const uint4*>(bth + boff + 8);
      *reinterpret_cast<uint4*>(&Bl[sr * 40 + sh])     = *reinterpret_cast<const uint4*>(btl + boff);
      *reinterpret_cast<uint4*>(&Bl[sr * 40 + sh + 8]) = *reinterpret_cast<const uint4*>(btl + boff + 8);
    }
    __syncthreads();
    bf16x8 afh[4], afl[4], bfh[4], bfl[4];
#pragma unroll
    for (int q = 0; q < 4; ++q) {
      afh[q] = *reinterpret_cast<const bf16x8*>(&Ah[(wr * 64 + q * 16 + fr) * 40 + quad * 8]);
      afl[q] = *reinterpret_cast<const bf16x8*>(&Al[(wr * 64 + q * 16 + fr) * 40 + quad * 8]);
      bfh[q] = *reinterpret_cast<const bf16x8*>(&Bh[(wc * 64 + q * 16 + fr) * 40 + quad * 8]);
      bfl[q] = *reinterpret_cast<const bf16x8*>(&Bl[(wc * 64 + q * 16 + fr) * 40 + quad * 8]);
    }
#pragma unroll
    for (int qr = 0; qr < 4; ++qr)
#pragma unroll
      for (int qc = 0; qc < 4; ++qc) {
        acc[qr][qc] = __builtin_amdgcn_mfma_f32_16x16x32_bf16(afl[qr], bfh[qc], acc[qr][qc], 0, 0, 0);
        acc[qr][qc] = __builtin_amdgcn_mfma_f32_16x16x32_bf16(afh[qr], bfl[qc], acc[qr][qc], 0, 0, 0);
        acc[qr][qc] = __builtin_amdgcn_mfma_f32_16x16x32_bf16(afh[qr], bfh[qc], acc[qr][qc], 0, 0, 0);
      }
    __syncthreads();
  }
  const int head = blockIdx.y * 2 + wc;
  // store Wh fp32
#pragma unroll
  for (int qr = 0; qr < 4; ++qr)
#pragma unroll
    for (int qc = 0; qc < 4; ++qc)
#pragma unroll
      for (int i = 0; i < 4; ++i) {
        int row = row0 + wr * 64 + qr * 16 + quad * 4 + i;
        int col = col0 + wc * 64 + qc * 16 + fr;
        Wh[(size_t)row * NFEAT + col] = acc[qr][qc][i];
      }
  // f1/f2: dot each row (64 cols of this head, all within this wave) with a1/a2
  const float* ah = a_heads + head * 2 * NHID;
  float a1v[4], a2v[4];
#pragma unroll
  for (int qc = 0; qc < 4; ++qc) { a1v[qc] = ah[qc * 16 + fr]; a2v[qc] = ah[NHID + qc * 16 + fr]; }
#pragma unroll
  for (int qr = 0; qr < 4; ++qr)
#pragma unroll
    for (int i = 0; i < 4; ++i) {
      float s1 = 0.f, s2 = 0.f;
#pragma unroll
      for (int qc = 0; qc < 4; ++qc) { s1 += acc[qr][qc][i] * a1v[qc]; s2 += acc[qr][qc][i] * a2v[qc]; }
#pragma unroll
      for (int m = 1; m < 16; m <<= 1) { s1 += __shfl_xor(s1, m, 64); s2 += __shfl_xor(s2, m, 64); }
      if (fr == 0) {
        int row = row0 + wr * 64 + qr * 16 + quad * 4 + i;
        f1[(head << 13) + row] = s1;
        f2[(head << 13) + row] = s2;
        atomicMax(&lmax[wc], encf(s2));
        atomicMax(&lmin[wc], ~encf(s2));
      }
    }
  // column sums over this wave's 64 rows
#pragma unroll
  for (int qc = 0; qc < 4; ++qc) {
    float v = 0.f;
#pragma unroll
    for (int qr = 0; qr < 4; ++qr)
#pragma unroll
      for (int i = 0; i < 4; ++i) v += acc[qr][qc][i];
    v += __shfl_xor(v, 16, 64);
    v += __shfl_xor(v, 32, 64);
    if (quad == 0) atomicAdd(&cs[wc][qc * 16 + fr], v);
  }
  __syncthreads();
  if (tid < 128) atomicAdd(&meanS[(blockIdx.y * 2 + (tid >> 6)) * NHID + (tid & 63)], cs[tid >> 6][tid & 63]);
  if (tid < 2) {
    atomicMax(&mm1[(blockIdx.y * 2 + tid) * 2], lmax[tid]);
    atomicMax(&mm1[(blockIdx.y * 2 + tid) * 2 + 1], lmin[tid]);
  }
}

// ---------------- GEMM2 fused: Wh2 = H @ W_out + f1b/f2b + colsums + minmax ----------------
__global__ __launch_bounds__(256) void gemm2_k(const float* __restrict__ H,
                                               const float* __restrict__ Wout,
                                               const float* __restrict__ a_out,
                                               float* __restrict__ Wh2,
                                               float* __restrict__ f1b,
                                               float* __restrict__ f2b,
                                               float* __restrict__ meanS2,
                                               uint* __restrict__ mm2) {
  const int row0 = blockIdx.x * 32;
  const int tid = threadIdx.x;
  __shared__ float As[32][33];
  __shared__ float Bs[32][40];
  __shared__ float cs[NCLASS];
  __shared__ uint lmax, lmin;
  if (tid < NCLASS) cs[tid] = 0.f;
  if (tid == 0) { lmax = 0u; lmin = 0u; }
  const int m = tid >> 3;
  const int n0 = (tid & 7) * 5;
  float acc[5] = {};
  for (int k0 = 0; k0 < NFEAT; k0 += 32) {
    {
      int kk = tid & 31, mq = tid >> 5;
#pragma unroll
      for (int r = 0; r < 4; ++r)
        As[kk][mq * 4 + r] = H[(size_t)(row0 + mq * 4 + r) * NFEAT + k0 + kk];
    }
    {
#pragma unroll
      for (int r = 0; r < 5; ++r) {
        int idx = tid + r * 256;
        if (idx < 1280) {
          int c = idx / 40, n = idx - c * 40;
          Bs[c][n] = Wout[(size_t)(k0 + c) * NCLASS + n];
        }
      }
    }
    __syncthreads();
#pragma unroll
    for (int kk = 0; kk < 32; ++kk) {
      float a = As[kk][m];
#pragma unroll
      for (int q = 0; q < 5; ++q) acc[q] += a * Bs[kk][n0 + q];
    }
    __syncthreads();
  }
#pragma unroll
  for (int q = 0; q < 5; ++q) Wh2[(size_t)(row0 + m) * NCLASS + n0 + q] = acc[q];
  float p1 = 0.f, p2 = 0.f;
#pragma unroll
  for (int q = 0; q < 5; ++q) {
    p1 += acc[q] * a_out[n0 + q];
    p2 += acc[q] * a_out[NCLASS + n0 + q];
  }
  p1 += __shfl_xor(p1, 1, 64); p1 += __shfl_xor(p1, 2, 64); p1 += __shfl_xor(p1, 4, 64);
  p2 += __shfl_xor(p2, 1, 64); p2 += __shfl_xor(p2, 2, 64); p2 += __shfl_xor(p2, 4, 64);
  if ((tid & 7) == 0) {
    f1b[row0 + m] = p1;
    f2b[row0 + m] = p2;
    atomicMax(&lmax, encf(p2));
    atomicMax(&lmin, ~encf(p2));
  }
#pragma unroll
  for (int q = 0; q < 5; ++q) atomicAdd(&cs[n0 + q], acc[q]);
  __syncthreads();
  if (tid < NCLASS) atomicAdd(&meanS2[tid], cs[tid]);
  if (tid == 0) { atomicMax(&mm2[0], lmax); atomicMax(&mm2[1], lmin); }
}

// ---------------- bucket histogram ----------------
__global__ __launch_bounds__(256) void hist_k(const float* __restrict__ f2, const uint* __restrict__ mm,
                                              int* __restrict__ hist) {
  int gid = blockIdx.x * 256 + threadIdx.x;
  int head = gid >> 13;
  float3 rg = load_rng(mm, head);
  atomicAdd(&hist[head * NB + bucket_of(f2[gid], rg.x, rg.y)], 1);
}

// ---------------- per-head exclusive prefix over NB buckets ----------------
__global__ __launch_bounds__(1024) void prefix_k(const int* __restrict__ hist, int* __restrict__ bs) {
  __shared__ int sb[NB];
  int head = blockIdx.x, tid = threadIdx.x;
#pragma unroll
  for (int r = 0; r < NB / 1024; ++r) sb[tid + r * 1024] = hist[head * NB + tid + r * 1024];
  __syncthreads();
  for (int st = 1; st < NB; st <<= 1) {
    int v[NB / 1024];
#pragma unroll
    for (int r = 0; r < NB / 1024; ++r) { int i = tid + r * 1024; v[r] = (i >= st) ? sb[i - st] : 0; }
    __syncthreads();
#pragma unroll
    for (int r = 0; r < NB / 1024; ++r) sb[tid + r * 1024] += v[r];
    __syncthreads();
  }
#pragma unroll
  for (int r = 0; r < NB / 1024; ++r) {
    int b = tid + r * 1024;
    bs[head * (NB + 1) + b] = b ? sb[b - 1] : 0;
  }
  if (tid == 0) bs[head * (NB + 1) + NB] = sb[NB - 1];
}

// ---------------- bucket scatter ----------------
__global__ __launch_bounds__(256) void scat_k(const float* __restrict__ f2, const uint* __restrict__ mm,
                                              const int* __restrict__ bs, int* __restrict__ cnt,
                                              int* __restrict__ idxs, float* __restrict__ f2s,
                                              float* __restrict__ g) {
  int gid = blockIdx.x * 256 + threadIdx.x;
  int head = gid >> 13, i = gid & 8191;
  float v = f2[gid];
  float3 rg = load_rng(mm, head);
  int b = bucket_of(v, rg.x, rg.y);
  int pos = bs[head * (NB + 1) + b] + atomicAdd(&cnt[head * NB + b], 1);
  int base = head << 13;
  idxs[base + pos] = i;
  f2s[base + pos] = v;
  g[base + pos] = expf(v - rg.z);
}

// ---------------- suffix scan phase A ----------------
template <int F, int LD, int COLSTEP>
__global__ __launch_bounds__(64) void scanA_k(const float* __restrict__ Wh,
                                              const float* __restrict__ g,
                                              const int* __restrict__ idxs,
                                              float* __restrict__ S,
                                              float* __restrict__ D,
                                              float* __restrict__ T_,
                                              float* __restrict__ Td) {
  int head = blockIdx.y, chunk = blockIdx.x;
  int lane = threadIdx.x;
  int base = head << 13;
  int kbase = base + chunk * CHUNK;
  int myj = idxs[kbase + lane];
  float myg = g[kbase + lane];
  float acc = 0.f, accD = 0.f;
#pragma unroll
  for (int kk = CHUNK - 1; kk >= 0; --kk) {
    int j = __shfl(myj, kk, 64);
    float gk = __shfl(myg, kk, 64);
    float w = (lane < F) ? Wh[(size_t)j * LD + head * COLSTEP + lane] : 0.f;
    acc += gk * w;
    accD += gk;
    if (lane < F) S[(size_t)(kbase + kk) * F + lane] = acc;
    if (lane == 0) D[kbase + kk] = accD;
  }
  if (lane < F) T_[(size_t)(head * NCHUNK + chunk) * F + lane] = acc;
  if (lane == 0) Td[head * NCHUNK + chunk] = accD;
}

// ---------------- suffix scan phase B: LDS Hillis-Steele over chunk totals ----------------
template <int F>
__global__ __launch_bounds__(1024) void scanB_k(float* __restrict__ T_, float* __restrict__ Td) {
  __shared__ float s[NCHUNK * F];
  __shared__ float td[NCHUNK];
  int head = blockIdx.x;
  int tid = threadIdx.x, slot = tid >> 6, lane = tid & 63;
#pragma unroll
  for (int r = 0; r < 8; ++r) {
    int c = r * 16 + slot;
    if (lane < F) s[c * F + lane] = T_[(size_t)(head * NCHUNK + c) * F + lane];
  }
  if (tid < NCHUNK) td[tid] = Td[head * NCHUNK + tid];
  __syncthreads();
  for (int st = 1; st < NCHUNK; st <<= 1) {
    float v[8];
    float tv = 0.f;
#pragma unroll
    for (int r = 0; r < 8; ++r) {
      int c = r * 16 + slot;
      v[r] = (lane < F && c + st < NCHUNK) ? s[(c + st) * F + lane] : 0.f;
    }
    if (tid < NCHUNK && tid + st < NCHUNK) tv = td[tid + st];
    __syncthreads();
#pragma unroll
    for (int r = 0; r < 8; ++r) {
      int c = r * 16 + slot;
      if (lane < F) s[c * F + lane] += v[r];
    }
    if (tid < NCHUNK) td[tid] += tv;
    __syncthreads();
  }
#pragma unroll
  for (int r = 0; r < 8; ++r) {
    int c = r * 16 + slot;
    if (lane < F) T_[(size_t)(head * NCHUNK + c) * F + lane] = s[c * F + lane];
  }
  if (tid < NCHUNK) Td[head * NCHUNK + tid] = td[tid];
}

// ---------------- layer-1 queries ----------------
__global__ __launch_bounds__(256) void query1_k(const float* __restrict__ f1,
                                                const float* __restrict__ f2s,
                                                const int* __restrict__ idxs,
                                                const float* __restrict__ Wh,
                                                const float* __restrict__ S,
                                                const float* __restrict__ D,
                                                const float* __restrict__ T_,
                                                const float* __restrict__ Td,
                                                const uint* __restrict__ mm,
                                                const int* __restrict__ bs,
                                                const float* __restrict__ meanS,
                                                float* __restrict__ H) {
  int w = blockIdx.x * 4 + (threadIdx.x >> 6);
  int lane = threadIdx.x & 63;
  int head = w & 7, i = w >> 3, base = head << 13;
  float t = f1[base + i];
  float3 rg = load_rng(mm, head);
  int B0 = bucket_of(-t, rg.x, rg.y);
  int p0 = bs[head * (NB + 1) + B0], p1 = bs[head * (NB + 1) + B0 + 1];
  float num = 0.f, den = 0.f;
  int cnt = N_NODES - p1;
  if (p1 < N_NODES) {
    int c = p1 >> 6;
    num = S[(size_t)(base + p1) * NHID + lane] +
          ((c + 1 < NCHUNK) ? T_[(size_t)(head * NCHUNK + c + 1) * NHID + lane] : 0.f);
    den = D[base + p1] + ((c + 1 < NCHUNK) ? Td[head * NCHUNK + c + 1] : 0.f);
  }
  for (int p = p0; p < p1; ++p) {
    float v = f2s[base + p];
    if (t + v > 0.f) {
      int j = idxs[base + p];
      float gk = expf(v - rg.z);
      num += gk * Wh[(size_t)j * NFEAT + head * NHID + lane];
      den += gk;
      ++cnt;
    }
  }
  float val = cnt ? num / den : meanS[head * NHID + lane] * (1.f / N_NODES);
  H[(size_t)i * NFEAT + head * NHID + lane] = (val > 0.f) ? val : expm1f(val);
}

// ---------------- layer-2 queries + elu + log_softmax ----------------
__global__ __launch_bounds__(256) void final_k(const float* __restrict__ f1b,
                                               const float* __restrict__ f2bs,
                                               const int* __restrict__ idx2,
                                               const float* __restrict__ Wh2,
                                               const float* __restrict__ S2,
                                               const float* __restrict__ D2,
                                               const float* __restrict__ T2,
                                               const float* __restrict__ Td2,
                                               const uint* __restrict__ mm2,
                                               const int* __restrict__ bs2,
                                               const float* __restrict__ meanS2,
                                               float* __restrict__ out) {
  int i = blockIdx.x * 4 + (threadIdx.x >> 6);
  int lane = threadIdx.x & 63;
  float t = f1b[i];
  float3 rg = load_rng(mm2, 0);
  int B0 = bucket_of(-t, rg.x, rg.y);
  int p0 = bs2[B0], p1 = bs2[B0 + 1];
  float num = 0.f, den = 0.f;
  int cnt = N_NODES - p1;
  if (p1 < N_NODES) {
    int c = p1 >> 6;
    num = (lane < NCLASS) ? (S2[(size_t)p1 * NCLASS + lane] +
                             ((c + 1 < NCHUNK) ? T2[(size_t)(c + 1) * NCLASS + lane] : 0.f))
                          : 0.f;
    den = D2[p1] + ((c + 1 < NCHUNK) ? Td2[c + 1] : 0.f);
  }
  for (int p = p0; p < p1; ++p) {
    float v = f2bs[p];
    if (t + v > 0.f) {
      int j = idx2[p];
      float gk = expf(v - rg.z);
      if (lane < NCLASS) num += gk * Wh2[(size_t)j * NCLASS + lane];
      den += gk;
      ++cnt;
    }
  }
  float o;
  if (lane < NCLASS) {
    float val = cnt ? num / den : meanS2[lane] * (1.f / N_NODES);
    o = (val > 0.f) ? val : expm1f(val);
  } else {
    o = -INFINITY;
  }
  float m = o;
#pragma unroll
  for (int msk = 32; msk; msk >>= 1) m = fmaxf(m, __shfl_xor(m, msk, 64));
  float e = (lane < NCLASS) ? expf(o - m) : 0.f;
#pragma unroll
  for (int msk = 32; msk; msk >>= 1) e += __shfl_xor(e, msk, 64);
  if (lane < NCLASS) out[(size_t)i * NCLASS + lane] = o - m - logf(e);
}

extern "C" void kernel_launch(void* const* d_in, const int* in_sizes, int n_in,
                              void* d_out, int out_size, void* d_ws, size_t ws_size,
                              hipStream_t stream) {
  const float* x       = (const float*)d_in[0];
  const float* W_heads = (const float*)d_in[2];
  const float* a_heads = (const float*)d_in[3];
  const float* W_out   = (const float*)d_in[4];
  const float* a_out   = (const float*)d_in[5];
  float* out = (float*)d_out;

  float* ws = (float*)d_ws;
  size_t o = 0;
  auto alloc = [&](size_t n) { float* p = ws + o; o += (n + 3) & ~(size_t)3; return p; };
  // xh/xl are dead after gemm1; S1 (same 16 MB) aliases them.
  float*  S1     = alloc((size_t)NHEADS * N_NODES * NHID);   // 16 MB
  ushort* xh     = (ushort*)S1;                              // alias (first 8 MB)
  ushort* xl     = (ushort*)(S1 + (size_t)N_NODES * NFEAT / 2);  // alias (second 8 MB)
  ushort* BTh    = (ushort*)alloc((size_t)NFEAT * NFEAT / 2);
  ushort* BTl    = (ushort*)alloc((size_t)NFEAT * NFEAT / 2);
  float*  Wh     = alloc((size_t)N_NODES * NFEAT);           // 16 MB fp32
  float*  H      = alloc((size_t)N_NODES * NFEAT);           // 16 MB
  float*  f1     = alloc(NHEADS * N_NODES);
  float*  f2     = alloc(NHEADS * N_NODES);
  float*  f2s    = alloc(NHEADS * N_NODES);
  int*    idxs   = (int*)alloc(NHEADS * N_NODES);
  float*  g1     = alloc(NHEADS * N_NODES);
  float*  D1     = alloc(NHEADS * N_NODES);
  float*  T1     = alloc(NHEADS * NCHUNK * NHID);
  float*  Td1    = alloc(NHEADS * NCHUNK);
  int*    bst1   = (int*)alloc(NHEADS * (NB + 1));
  float*  Wh2    = alloc((size_t)N_NODES * NCLASS);
  float*  S2     = alloc((size_t)N_NODES * NCLASS);
  float*  f1b    = alloc(N_NODES);
  float*  f2b    = alloc(N_NODES);
  float*  f2bs   = alloc(N_NODES);
  int*    idx2   = (int*)alloc(N_NODES);
  float*  g2     = alloc(N_NODES);
  float*  D2     = alloc(N_NODES);
  float*  T2     = alloc(NCHUNK * NCLASS);
  float*  Td2    = alloc(NCHUNK);
  int*    bst2   = (int*)alloc(NB + 1);
  // ---- contiguous zero region ----
  float*  zbase  = ws + o;
  int*    hist1  = (int*)alloc((size_t)NHEADS * NB);
  int*    cnt1   = (int*)alloc((size_t)NHEADS * NB);
  int*    hist2  = (int*)alloc(NB);
  int*    cnt2   = (int*)alloc(NB);
  uint*   mm1    = (uint*)alloc(16);
  uint*   mm2    = (uint*)alloc(4);
  float*  meanS1 = alloc(NHEADS * NHID);
  float*  meanS2 = alloc(64);
  size_t zbytes = (size_t)((ws + o) - zbase) * sizeof(float);
  hipMemsetAsync(zbase, 0, zbytes, stream);

  // ---- layer 1 ----
  prep_k<<<1024 + 2048, 256, 0, stream>>>(x, W_heads, BTh, BTl, xh, xl);
  gemm1_k<<<dim3(64, 4), 256, 0, stream>>>(xh, xl, BTh, BTl, a_heads, Wh, f1, f2, meanS1, mm1);
  hist_k<<<(NHEADS * N_NODES) / 256, 256, 0, stream>>>(f2, mm1, hist1);
  prefix_k<<<NHEADS, 1024, 0, stream>>>(hist1, bst1);
  scat_k<<<(NHEADS * N_NODES) / 256, 256, 0, stream>>>(f2, mm1, bst1, cnt1, idxs, f2s, g1);
  scanA_k<NHID, NFEAT, NHID><<<dim3(NCHUNK, NHEADS), 64, 0, stream>>>(Wh, g1, idxs, S1, D1, T1, Td1);
  scanB_k<NHID><<<NHEADS, 1024, 0, stream>>>(T1, Td1);
  query1_k<<<16384, 256, 0, stream>>>(f1, f2s, idxs, Wh, S1, D1, T1, Td1, mm1, bst1, meanS1, H);

  // ---- layer 2 ----
  gemm2_k<<<256, 256, 0, stream>>>(H, W_out, a_out, Wh2, f1b, f2b, meanS2, mm2);
  hist_k<<<N_NODES / 256, 256, 0, stream>>>(f2b, mm2, hist2);
  prefix_k<<<1, 1024, 0, stream>>>(hist2, bst2);
  scat_k<<<N_NODES / 256, 256, 0, stream>>>(f2b, mm2, bst2, cnt2, idx2, f2bs, g2);
  scanA_k<NCLASS, NCLASS, 0><<<dim3(NCHUNK, 1), 64, 0, stream>>>(Wh2, g2, idx2, S2, D2, T2, Td2);
  scanB_k<NCLASS><<<1, 1024, 0, stream>>>(T2, Td2);
  final_k<<<2048, 256, 0, stream>>>(f1b, f2bs, idx2, Wh2, S2, D2, T2, Td2, mm2, bst2, meanS2, out);
}

// Round 5
// 535.788 us; speedup vs baseline: 1.5137x; 1.0472x over previous
//
#include <hip/hip_runtime.h>
#include <math.h>

#define N_NODES 8192
#define NFEAT 512
#define NHID 64
#define NHEADS 8
#define NCLASS 40
#define NCHUNK 128
#define CHUNK 64
#define NB 4096

using bf16x8 = __attribute__((ext_vector_type(8))) short;
using f32x4 = __attribute__((ext_vector_type(4))) float;

// ---- helpers ----
__device__ __forceinline__ ushort f2b(float f) {  // fp32 -> bf16 RNE
  uint u = __builtin_bit_cast(uint, f);
  u += 0x7FFFu + ((u >> 16) & 1u);
  return (ushort)(u >> 16);
}
__device__ __forceinline__ float b2f(ushort h) {
  uint u = (uint)h << 16;
  return __builtin_bit_cast(float, u);
}
__device__ __forceinline__ uint encf(float f) {  // sortable-ascending uint
  uint u = __builtin_bit_cast(uint, f);
  return u ^ ((u >> 31) ? 0xFFFFFFFFu : 0x80000000u);
}
__device__ __forceinline__ float decf(uint u) {
  u ^= ((u >> 31) ? 0x80000000u : 0xFFFFFFFFu);
  return __builtin_bit_cast(float, u);
}
__device__ __forceinline__ float3 load_rng(const uint* mm, int head) {
  float h = decf(mm[head * 2]);        // max f2
  float l = decf(~mm[head * 2 + 1]);   // min f2 (stored as max of ~enc)
  float scale = (float)NB / fmaxf(h - l, 1e-30f);
  return make_float3(l, scale, h);
}
__device__ __forceinline__ int bucket_of(float v, float lo, float scale) {
  float u = fminf(fmaxf((v - lo) * scale, 0.f), (float)(NB - 1));
  return (int)u;
}

// ---------------- prep: split B' (=W transposed) into bf16 hi/lo planes + zero scratch ----
__global__ __launch_bounds__(256) void prep_k(const float* __restrict__ W_heads,
                                              ushort* __restrict__ bth,
                                              ushort* __restrict__ btl,
                                              float* __restrict__ zbase,
                                              int zcount) {
  int gid = blockIdx.x * 256 + threadIdx.x;
  // BT[n][c] = W_heads[h][c][f], n = h*64+f   (512x512), split hi/lo
  int n = gid >> 9, c = gid & 511;
  int h = n >> 6, f = n & 63;
  float w = W_heads[((size_t)h * NFEAT + c) * NHID + f];
  ushort hh = f2b(w);
  bth[gid] = hh;
  btl[gid] = f2b(w - b2f(hh));
  if (gid < zcount) zbase[gid] = 0.f;  // zero hist/cnt/mm/meanS region
}

// ---------------- GEMM1: Wh(fp32) = x @ B' via split-bf16 MFMA (3 terms), 128x128 tiles ----
// A-operand split from fp32 x happens inline during staging.
// Fused epilogue: f1/f2 row dots, per-head f2 min/max, per-head column sums (meanS).
__global__ __launch_bounds__(256) void gemm1_k(const float* __restrict__ x,
                                               const ushort* __restrict__ bth,
                                               const ushort* __restrict__ btl,
                                               const float* __restrict__ a_heads,
                                               float* __restrict__ Wh,
                                               float* __restrict__ f1,
                                               float* __restrict__ f2,
                                               float* __restrict__ meanS,
                                               uint* __restrict__ mm1) {
  const int row0 = blockIdx.x * 128, col0 = blockIdx.y * 128;
  const int tid = threadIdx.x;
  const int wave = tid >> 6, lane = tid & 63;
  const int wr = wave >> 1, wc = wave & 1;
  __shared__ ushort Ah[128 * 40], Al[128 * 40], Bh[128 * 40], Bl[128 * 40];
  __shared__ float cs[2][64];
  __shared__ uint lmax[2], lmin[2];
  if (tid < 2) { lmax[tid] = 0u; lmin[tid] = 0u; }
  if (tid < 128) cs[tid >> 6][tid & 63] = 0.f;
  f32x4 acc[4][4] = {};
  const int sr = tid >> 1, sh = (tid & 1) * 16;
  const int fr = lane & 15, quad = lane >> 4;
  for (int k0 = 0; k0 < NFEAT; k0 += 32) {
    {
      // A: read 16 fp32 of x, split into hi/lo bf16, write both LDS planes
      const float* xs = x + (size_t)(row0 + sr) * NFEAT + k0 + sh;
      float av[16];
      *reinterpret_cast<float4*>(&av[0])  = *reinterpret_cast<const float4*>(xs);
      *reinterpret_cast<float4*>(&av[4])  = *reinterpret_cast<const float4*>(xs + 4);
      *reinterpret_cast<float4*>(&av[8])  = *reinterpret_cast<const float4*>(xs + 8);
      *reinterpret_cast<float4*>(&av[12]) = *reinterpret_cast<const float4*>(xs + 12);
      uint uh[8], ul[8];
#pragma unroll
      for (int q = 0; q < 8; ++q) {
        ushort h0 = f2b(av[2 * q]), h1 = f2b(av[2 * q + 1]);
        ushort l0 = f2b(av[2 * q] - b2f(h0)), l1 = f2b(av[2 * q + 1] - b2f(h1));
        uh[q] = (uint)h0 | ((uint)h1 << 16);
        ul[q] = (uint)l0 | ((uint)l1 << 16);
      }
      *reinterpret_cast<uint4*>(&Ah[sr * 40 + sh])     = make_uint4(uh[0], uh[1], uh[2], uh[3]);
      *reinterpret_cast<uint4*>(&Ah[sr * 40 + sh + 8]) = make_uint4(uh[4], uh[5], uh[6], uh[7]);
      *reinterpret_cast<uint4*>(&Al[sr * 40 + sh])     = make_uint4(ul[0], ul[1], ul[2], ul[3]);
      *reinterpret_cast<uint4*>(&Al[sr * 40 + sh + 8]) = make_uint4(ul[4], ul[5], ul[6], ul[7]);
      // B: pre-split planes, straight copy
      size_t boff = (size_t)(col0 + sr) * NFEAT + k0 + sh;
      *reinterpret_cast<uint4*>(&Bh[sr * 40 + sh])     = *reinterpret_cast<const uint4*>(bth + boff);
      *reinterpret_cast<uint4*>(&Bh[sr * 40 + sh + 8]) = *reinterpret_cast<const uint4*>(bth + boff + 8);
      *reinterpret_cast<uint4*>(&Bl[sr * 40 + sh])     = *reinterpret_cast<const uint4*>(btl + boff);
      *reinterpret_cast<uint4*>(&Bl[sr * 40 + sh + 8]) = *reinterpret_cast<const uint4*>(btl + boff + 8);
    }
    __syncthreads();
    bf16x8 afh[4], afl[4], bfh[4], bfl[4];
#pragma unroll
    for (int q = 0; q < 4; ++q) {
      afh[q] = *reinterpret_cast<const bf16x8*>(&Ah[(wr * 64 + q * 16 + fr) * 40 + quad * 8]);
      afl[q] = *reinterpret_cast<const bf16x8*>(&Al[(wr * 64 + q * 16 + fr) * 40 + quad * 8]);
      bfh[q] = *reinterpret_cast<const bf16x8*>(&Bh[(wc * 64 + q * 16 + fr) * 40 + quad * 8]);
      bfl[q] = *reinterpret_cast<const bf16x8*>(&Bl[(wc * 64 + q * 16 + fr) * 40 + quad * 8]);
    }
#pragma unroll
    for (int qr = 0; qr < 4; ++qr)
#pragma unroll
      for (int qc = 0; qc < 4; ++qc) {
        acc[qr][qc] = __builtin_amdgcn_mfma_f32_16x16x32_bf16(afl[qr], bfh[qc], acc[qr][qc], 0, 0, 0);
        acc[qr][qc] = __builtin_amdgcn_mfma_f32_16x16x32_bf16(afh[qr], bfl[qc], acc[qr][qc], 0, 0, 0);
        acc[qr][qc] = __builtin_amdgcn_mfma_f32_16x16x32_bf16(afh[qr], bfh[qc], acc[qr][qc], 0, 0, 0);
      }
    __syncthreads();
  }
  const int head = blockIdx.y * 2 + wc;
  // store Wh fp32
#pragma unroll
  for (int qr = 0; qr < 4; ++qr)
#pragma unroll
    for (int qc = 0; qc < 4; ++qc)
#pragma unroll
      for (int i = 0; i < 4; ++i) {
        int row = row0 + wr * 64 + qr * 16 + quad * 4 + i;
        int col = col0 + wc * 64 + qc * 16 + fr;
        Wh[(size_t)row * NFEAT + col] = acc[qr][qc][i];
      }
  // f1/f2: dot each row (64 cols of this head, all within this wave) with a1/a2
  const float* ah = a_heads + head * 2 * NHID;
  float a1v[4], a2v[4];
#pragma unroll
  for (int qc = 0; qc < 4; ++qc) { a1v[qc] = ah[qc * 16 + fr]; a2v[qc] = ah[NHID + qc * 16 + fr]; }
#pragma unroll
  for (int qr = 0; qr < 4; ++qr)
#pragma unroll
    for (int i = 0; i < 4; ++i) {
      float s1 = 0.f, s2 = 0.f;
#pragma unroll
      for (int qc = 0; qc < 4; ++qc) { s1 += acc[qr][qc][i] * a1v[qc]; s2 += acc[qr][qc][i] * a2v[qc]; }
#pragma unroll
      for (int m = 1; m < 16; m <<= 1) { s1 += __shfl_xor(s1, m, 64); s2 += __shfl_xor(s2, m, 64); }
      if (fr == 0) {
        int row = row0 + wr * 64 + qr * 16 + quad * 4 + i;
        f1[(head << 13) + row] = s1;
        f2[(head << 13) + row] = s2;
        atomicMax(&lmax[wc], encf(s2));
        atomicMax(&lmin[wc], ~encf(s2));
      }
    }
  // column sums over this wave's 64 rows
#pragma unroll
  for (int qc = 0; qc < 4; ++qc) {
    float v = 0.f;
#pragma unroll
    for (int qr = 0; qr < 4; ++qr)
#pragma unroll
      for (int i = 0; i < 4; ++i) v += acc[qr][qc][i];
    v += __shfl_xor(v, 16, 64);
    v += __shfl_xor(v, 32, 64);
    if (quad == 0) atomicAdd(&cs[wc][qc * 16 + fr], v);
  }
  __syncthreads();
  if (tid < 128) atomicAdd(&meanS[(blockIdx.y * 2 + (tid >> 6)) * NHID + (tid & 63)], cs[tid >> 6][tid & 63]);
  if (tid < 2) {
    atomicMax(&mm1[(blockIdx.y * 2 + tid) * 2], lmax[tid]);
    atomicMax(&mm1[(blockIdx.y * 2 + tid) * 2 + 1], lmin[tid]);
  }
}

// ---------------- GEMM2 fused: Wh2 = H @ W_out + f1b/f2b + colsums + minmax ----------------
__global__ __launch_bounds__(256) void gemm2_k(const float* __restrict__ H,
                                               const float* __restrict__ Wout,
                                               const float* __restrict__ a_out,
                                               float* __restrict__ Wh2,
                                               float* __restrict__ f1b,
                                               float* __restrict__ f2b,
                                               float* __restrict__ meanS2,
                                               uint* __restrict__ mm2) {
  const int row0 = blockIdx.x * 32;
  const int tid = threadIdx.x;
  __shared__ float As[32][33];
  __shared__ float Bs[32][40];
  __shared__ float cs[NCLASS];
  __shared__ uint lmax, lmin;
  if (tid < NCLASS) cs[tid] = 0.f;
  if (tid == 0) { lmax = 0u; lmin = 0u; }
  const int m = tid >> 3;
  const int n0 = (tid & 7) * 5;
  float acc[5] = {};
  for (int k0 = 0; k0 < NFEAT; k0 += 32) {
    {
      int kk = tid & 31, mq = tid >> 5;
#pragma unroll
      for (int r = 0; r < 4; ++r)
        As[kk][mq * 4 + r] = H[(size_t)(row0 + mq * 4 + r) * NFEAT + k0 + kk];
    }
    {
#pragma unroll
      for (int r = 0; r < 5; ++r) {
        int idx = tid + r * 256;
        if (idx < 1280) {
          int c = idx / 40, n = idx - c * 40;
          Bs[c][n] = Wout[(size_t)(k0 + c) * NCLASS + n];
        }
      }
    }
    __syncthreads();
#pragma unroll
    for (int kk = 0; kk < 32; ++kk) {
      float a = As[kk][m];
#pragma unroll
      for (int q = 0; q < 5; ++q) acc[q] += a * Bs[kk][n0 + q];
    }
    __syncthreads();
  }
#pragma unroll
  for (int q = 0; q < 5; ++q) Wh2[(size_t)(row0 + m) * NCLASS + n0 + q] = acc[q];
  float p1 = 0.f, p2 = 0.f;
#pragma unroll
  for (int q = 0; q < 5; ++q) {
    p1 += acc[q] * a_out[n0 + q];
    p2 += acc[q] * a_out[NCLASS + n0 + q];
  }
  p1 += __shfl_xor(p1, 1, 64); p1 += __shfl_xor(p1, 2, 64); p1 += __shfl_xor(p1, 4, 64);
  p2 += __shfl_xor(p2, 1, 64); p2 += __shfl_xor(p2, 2, 64); p2 += __shfl_xor(p2, 4, 64);
  if ((tid & 7) == 0) {
    f1b[row0 + m] = p1;
    f2b[row0 + m] = p2;
    atomicMax(&lmax, encf(p2));
    atomicMax(&lmin, ~encf(p2));
  }
#pragma unroll
  for (int q = 0; q < 5; ++q) atomicAdd(&cs[n0 + q], acc[q]);
  __syncthreads();
  if (tid < NCLASS) atomicAdd(&meanS2[tid], cs[tid]);
  if (tid == 0) { atomicMax(&mm2[0], lmax); atomicMax(&mm2[1], lmin); }
}

// ---------------- bucket histogram ----------------
__global__ __launch_bounds__(256) void hist_k(const float* __restrict__ f2, const uint* __restrict__ mm,
                                              int* __restrict__ hist) {
  int gid = blockIdx.x * 256 + threadIdx.x;
  int head = gid >> 13;
  float3 rg = load_rng(mm, head);
  atomicAdd(&hist[head * NB + bucket_of(f2[gid], rg.x, rg.y)], 1);
}

// ---------------- per-head exclusive prefix over NB buckets ----------------
__global__ __launch_bounds__(1024) void prefix_k(const int* __restrict__ hist, int* __restrict__ bs) {
  __shared__ int sb[NB];
  int head = blockIdx.x, tid = threadIdx.x;
#pragma unroll
  for (int r = 0; r < NB / 1024; ++r) sb[tid + r * 1024] = hist[head * NB + tid + r * 1024];
  __syncthreads();
  for (int st = 1; st < NB; st <<= 1) {
    int v[NB / 1024];
#pragma unroll
    for (int r = 0; r < NB / 1024; ++r) { int i = tid + r * 1024; v[r] = (i >= st) ? sb[i - st] : 0; }
    __syncthreads();
#pragma unroll
    for (int r = 0; r < NB / 1024; ++r) sb[tid + r * 1024] += v[r];
    __syncthreads();
  }
#pragma unroll
  for (int r = 0; r < NB / 1024; ++r) {
    int b = tid + r * 1024;
    bs[head * (NB + 1) + b] = b ? sb[b - 1] : 0;
  }
  if (tid == 0) bs[head * (NB + 1) + NB] = sb[NB - 1];
}

// ---------------- bucket scatter ----------------
__global__ __launch_bounds__(256) void scat_k(const float* __restrict__ f2, const uint* __restrict__ mm,
                                              const int* __restrict__ bs, int* __restrict__ cnt,
                                              int* __restrict__ idxs, float* __restrict__ f2s,
                                              float* __restrict__ g) {
  int gid = blockIdx.x * 256 + threadIdx.x;
  int head = gid >> 13, i = gid & 8191;
  float v = f2[gid];
  float3 rg = load_rng(mm, head);
  int b = bucket_of(v, rg.x, rg.y);
  int pos = bs[head * (NB + 1) + b] + atomicAdd(&cnt[head * NB + b], 1);
  int base = head << 13;
  idxs[base + pos] = i;
  f2s[base + pos] = v;
  g[base + pos] = expf(v - rg.z);
}

// ---------------- suffix scan phase A: one 256-thread block per chunk, 4 waves x 16 elems ----
template <int F, int LD, int COLSTEP>
__global__ __launch_bounds__(256) void scanA_k(const float* __restrict__ Wh,
                                               const float* __restrict__ g,
                                               const int* __restrict__ idxs,
                                               float* __restrict__ S,
                                               float* __restrict__ D,
                                               float* __restrict__ T_,
                                               float* __restrict__ Td) {
  constexpr int PAD = (F == 64) ? 66 : 42;
  const int head = blockIdx.y, chunk = blockIdx.x;
  const int tid = threadIdx.x, w = tid >> 6, lane = tid & 63;
  const int base = head << 13;
  const int kbase = base + chunk * CHUNK;
  __shared__ float Sloc[64][PAD];
  __shared__ float Dloc[64];
  __shared__ float wtot[4][PAD];
  __shared__ float wtotD[4];
  int myj = 0; float myg = 0.f;
  if (lane < 16) {
    myj = idxs[kbase + w * 16 + lane];
    myg = g[kbase + w * 16 + lane];
  }
  float acc = 0.f, accD = 0.f;
#pragma unroll
  for (int kk = 15; kk >= 0; --kk) {
    int j = __shfl(myj, kk, 64);
    float gk = __shfl(myg, kk, 64);
    float wv = (lane < F) ? Wh[(size_t)j * LD + head * COLSTEP + lane] : 0.f;
    acc += gk * wv;
    accD += gk;
    if (lane < F) Sloc[w * 16 + kk][lane] = acc;
    if (lane == 0) Dloc[w * 16 + kk] = accD;
  }
  if (lane < F) wtot[w][lane] = acc;
  if (lane == 0) wtotD[w] = accD;
  __syncthreads();
  float off = 0.f, offD = 0.f;
#pragma unroll
  for (int w2 = 1; w2 < 4; ++w2) {
    if (w + w2 < 4) {
      off += (lane < F) ? wtot[w + w2][lane] : 0.f;
      offD += wtotD[w + w2];
    }
  }
#pragma unroll
  for (int kk = 0; kk < 16; ++kk) {
    int e = w * 16 + kk;
    if (lane < F) S[(size_t)(kbase + e) * F + lane] = Sloc[e][lane] + off;
    if (lane == 0) D[kbase + e] = Dloc[e] + offD;
  }
  if (w == 0) {
    if (lane < F) T_[(size_t)(head * NCHUNK + chunk) * F + lane] = wtot[0][lane] + off;
    if (lane == 0) Td[head * NCHUNK + chunk] = wtotD[0] + offD;
  }
}

// ---------------- suffix scan phase B: LDS Hillis-Steele over chunk totals ----------------
template <int F>
__global__ __launch_bounds__(1024) void scanB_k(float* __restrict__ T_, float* __restrict__ Td) {
  __shared__ float s[NCHUNK * F];
  __shared__ float td[NCHUNK];
  int head = blockIdx.x;
  int tid = threadIdx.x, slot = tid >> 6, lane = tid & 63;
#pragma unroll
  for (int r = 0; r < 8; ++r) {
    int c = r * 16 + slot;
    if (lane < F) s[c * F + lane] = T_[(size_t)(head * NCHUNK + c) * F + lane];
  }
  if (tid < NCHUNK) td[tid] = Td[head * NCHUNK + tid];
  __syncthreads();
  for (int st = 1; st < NCHUNK; st <<= 1) {
    float v[8];
    float tv = 0.f;
#pragma unroll
    for (int r = 0; r < 8; ++r) {
      int c = r * 16 + slot;
      v[r] = (lane < F && c + st < NCHUNK) ? s[(c + st) * F + lane] : 0.f;
    }
    if (tid < NCHUNK && tid + st < NCHUNK) tv = td[tid + st];
    __syncthreads();
#pragma unroll
    for (int r = 0; r < 8; ++r) {
      int c = r * 16 + slot;
      if (lane < F) s[c * F + lane] += v[r];
    }
    if (tid < NCHUNK) td[tid] += tv;
    __syncthreads();
  }
#pragma unroll
  for (int r = 0; r < 8; ++r) {
    int c = r * 16 + slot;
    if (lane < F) T_[(size_t)(head * NCHUNK + c) * F + lane] = s[c * F + lane];
  }
  if (tid < NCHUNK) Td[head * NCHUNK + tid] = td[tid];
}

// ---------------- layer-1 queries ----------------
__global__ __launch_bounds__(256) void query1_k(const float* __restrict__ f1,
                                                const float* __restrict__ f2s,
                                                const int* __restrict__ idxs,
                                                const float* __restrict__ Wh,
                                                const float* __restrict__ S,
                                                const float* __restrict__ D,
                                                const float* __restrict__ T_,
                                                const float* __restrict__ Td,
                                                const uint* __restrict__ mm,
                                                const int* __restrict__ bs,
                                                const float* __restrict__ meanS,
                                                float* __restrict__ H) {
  int w = blockIdx.x * 4 + (threadIdx.x >> 6);
  int lane = threadIdx.x & 63;
  int head = w & 7, i = w >> 3, base = head << 13;
  float t = f1[base + i];
  float3 rg = load_rng(mm, head);
  int B0 = bucket_of(-t, rg.x, rg.y);
  int p0 = bs[head * (NB + 1) + B0], p1 = bs[head * (NB + 1) + B0 + 1];
  float num = 0.f, den = 0.f;
  int cnt = N_NODES - p1;
  if (p1 < N_NODES) {
    int c = p1 >> 6;
    num = S[(size_t)(base + p1) * NHID + lane] +
          ((c + 1 < NCHUNK) ? T_[(size_t)(head * NCHUNK + c + 1) * NHID + lane] : 0.f);
    den = D[base + p1] + ((c + 1 < NCHUNK) ? Td[head * NCHUNK + c + 1] : 0.f);
  }
  for (int p = p0; p < p1; ++p) {
    float v = f2s[base + p];
    if (t + v > 0.f) {
      int j = idxs[base + p];
      float gk = expf(v - rg.z);
      num += gk * Wh[(size_t)j * NFEAT + head * NHID + lane];
      den += gk;
      ++cnt;
    }
  }
  float val = cnt ? num / den : meanS[head * NHID + lane] * (1.f / N_NODES);
  H[(size_t)i * NFEAT + head * NHID + lane] = (val > 0.f) ? val : expm1f(val);
}

// ---------------- layer-2 queries + elu + log_softmax ----------------
__global__ __launch_bounds__(256) void final_k(const float* __restrict__ f1b,
                                               const float* __restrict__ f2bs,
                                               const int* __restrict__ idx2,
                                               const float* __restrict__ Wh2,
                                               const float* __restrict__ S2,
                                               const float* __restrict__ D2,
                                               const float* __restrict__ T2,
                                               const float* __restrict__ Td2,
                                               const uint* __restrict__ mm2,
                                               const int* __restrict__ bs2,
                                               const float* __restrict__ meanS2,
                                               float* __restrict__ out) {
  int i = blockIdx.x * 4 + (threadIdx.x >> 6);
  int lane = threadIdx.x & 63;
  float t = f1b[i];
  float3 rg = load_rng(mm2, 0);
  int B0 = bucket_of(-t, rg.x, rg.y);
  int p0 = bs2[B0], p1 = bs2[B0 + 1];
  float num = 0.f, den = 0.f;
  int cnt = N_NODES - p1;
  if (p1 < N_NODES) {
    int c = p1 >> 6;
    num = (lane < NCLASS) ? (S2[(size_t)p1 * NCLASS + lane] +
                             ((c + 1 < NCHUNK) ? T2[(size_t)(c + 1) * NCLASS + lane] : 0.f))
                          : 0.f;
    den = D2[p1] + ((c + 1 < NCHUNK) ? Td2[c + 1] : 0.f);
  }
  for (int p = p0; p < p1; ++p) {
    float v = f2bs[p];
    if (t + v > 0.f) {
      int j = idx2[p];
      float gk = expf(v - rg.z);
      if (lane < NCLASS) num += gk * Wh2[(size_t)j * NCLASS + lane];
      den += gk;
      ++cnt;
    }
  }
  float o;
  if (lane < NCLASS) {
    float val = cnt ? num / den : meanS2[lane] * (1.f / N_NODES);
    o = (val > 0.f) ? val : expm1f(val);
  } else {
    o = -INFINITY;
  }
  float m = o;
#pragma unroll
  for (int msk = 32; msk; msk >>= 1) m = fmaxf(m, __shfl_xor(m, msk, 64));
  float e = (lane < NCLASS) ? expf(o - m) : 0.f;
#pragma unroll
  for (int msk = 32; msk; msk >>= 1) e += __shfl_xor(e, msk, 64);
  if (lane < NCLASS) out[(size_t)i * NCLASS + lane] = o - m - logf(e);
}

extern "C" void kernel_launch(void* const* d_in, const int* in_sizes, int n_in,
                              void* d_out, int out_size, void* d_ws, size_t ws_size,
                              hipStream_t stream) {
  const float* x       = (const float*)d_in[0];
  const float* W_heads = (const float*)d_in[2];
  const float* a_heads = (const float*)d_in[3];
  const float* W_out   = (const float*)d_in[4];
  const float* a_out   = (const float*)d_in[5];
  float* out = (float*)d_out;

  float* ws = (float*)d_ws;
  size_t o = 0;
  auto alloc = [&](size_t n) { float* p = ws + o; o += (n + 3) & ~(size_t)3; return p; };
  float*  S1     = alloc((size_t)NHEADS * N_NODES * NHID);   // 16 MB
  ushort* BTh    = (ushort*)alloc((size_t)NFEAT * NFEAT / 2);
  ushort* BTl    = (ushort*)alloc((size_t)NFEAT * NFEAT / 2);
  float*  Wh     = alloc((size_t)N_NODES * NFEAT);           // 16 MB fp32
  float*  H      = alloc((size_t)N_NODES * NFEAT);           // 16 MB
  float*  f1     = alloc(NHEADS * N_NODES);
  float*  f2     = alloc(NHEADS * N_NODES);
  float*  f2s    = alloc(NHEADS * N_NODES);
  int*    idxs   = (int*)alloc(NHEADS * N_NODES);
  float*  g1     = alloc(NHEADS * N_NODES);
  float*  D1     = alloc(NHEADS * N_NODES);
  float*  T1     = alloc(NHEADS * NCHUNK * NHID);
  float*  Td1    = alloc(NHEADS * NCHUNK);
  int*    bst1   = (int*)alloc(NHEADS * (NB + 1));
  float*  Wh2    = alloc((size_t)N_NODES * NCLASS);
  float*  S2     = alloc((size_t)N_NODES * NCLASS);
  float*  f1b    = alloc(N_NODES);
  float*  f2b    = alloc(N_NODES);
  float*  f2bs   = alloc(N_NODES);
  int*    idx2   = (int*)alloc(N_NODES);
  float*  g2     = alloc(N_NODES);
  float*  D2     = alloc(N_NODES);
  float*  T2     = alloc(NCHUNK * NCLASS);
  float*  Td2    = alloc(NCHUNK);
  int*    bst2   = (int*)alloc(NB + 1);
  // ---- contiguous zero region (zeroed by prep_k) ----
  float*  zbase  = ws + o;
  int*    hist1  = (int*)alloc((size_t)NHEADS * NB);
  int*    cnt1   = (int*)alloc((size_t)NHEADS * NB);
  int*    hist2  = (int*)alloc(NB);
  int*    cnt2   = (int*)alloc(NB);
  uint*   mm1    = (uint*)alloc(16);
  uint*   mm2    = (uint*)alloc(4);
  float*  meanS1 = alloc(NHEADS * NHID);
  float*  meanS2 = alloc(64);
  int zcount = (int)((ws + o) - zbase);

  // ---- layer 1 ----
  prep_k<<<1024, 256, 0, stream>>>(W_heads, BTh, BTl, zbase, zcount);
  gemm1_k<<<dim3(64, 4), 256, 0, stream>>>(x, BTh, BTl, a_heads, Wh, f1, f2, meanS1, mm1);
  hist_k<<<(NHEADS * N_NODES) / 256, 256, 0, stream>>>(f2, mm1, hist1);
  prefix_k<<<NHEADS, 1024, 0, stream>>>(hist1, bst1);
  scat_k<<<(NHEADS * N_NODES) / 256, 256, 0, stream>>>(f2, mm1, bst1, cnt1, idxs, f2s, g1);
  scanA_k<NHID, NFEAT, NHID><<<dim3(NCHUNK, NHEADS), 256, 0, stream>>>(Wh, g1, idxs, S1, D1, T1, Td1);
  scanB_k<NHID><<<NHEADS, 1024, 0, stream>>>(T1, Td1);
  query1_k<<<16384, 256, 0, stream>>>(f1, f2s, idxs, Wh, S1, D1, T1, Td1, mm1, bst1, meanS1, H);

  // ---- layer 2 ----
  gemm2_k<<<256, 256, 0, stream>>>(H, W_out, a_out, Wh2, f1b, f2b, meanS2, mm2);
  hist_k<<<N_NODES / 256, 256, 0, stream>>>(f2b, mm2, hist2);
  prefix_k<<<1, 1024, 0, stream>>>(hist2, bst2);
  scat_k<<<N_NODES / 256, 256, 0, stream>>>(f2b, mm2, bst2, cnt2, idx2, f2bs, g2);
  scanA_k<NCLASS, NCLASS, 0><<<dim3(NCHUNK, 1), 256, 0, stream>>>(Wh2, g2, idx2, S2, D2, T2, Td2);
  scanB_k<NCLASS><<<1, 1024, 0, stream>>>(T2, Td2);
  final_k<<<2048, 256, 0, stream>>>(f1b, f2bs, idx2, Wh2, S2, D2, T2, Td2, mm2, bst2, meanS2, out);
}